// Round 5
// baseline (4108.924 us; speedup 1.0000x reference)
//
#include <hip/hip_runtime.h>
#include <math.h>

#define NNODES 16000
#define NEDGES 256000

// ---------------- ws layout (float element offsets) ----------------
// cg | y0 | y1 | sc0 | sc1 | BIG{ Agg(<=21 rows) ; x0n/x1n aliased after Agg9 } | CSR ints
// x0n/x1n are written ONLY by k_node_post<0> and read ONLY by k_node_pre<1>;
// k_node_post<1> must NOT write them (they alias block-1 Agg rows).
#define WS_CG   0
#define WS_Y0   512
#define WS_Y1   (WS_Y0 + NNODES*64)
#define WS_SC0  (WS_Y1 + NNODES*192)
#define WS_SC1  (WS_SC0 + NNODES*64)
#define WS_BIG  (WS_SC1 + NNODES*192)
#define WS_AGG  WS_BIG
#define WS_X0N  (WS_BIG + NNODES*9*64)   // alive only node_post<0> -> node_pre<1>
#define WS_X1N  (WS_X0N + NNODES*64)
#define WS_CSR  (WS_BIG + NNODES*21*64)  // int region starts here
// ints: counts[N] | off[N+1] | cursor[N] | eidx[E]  = 304001 ints ~ 1.2 MB
// total ~ 120 MB

// CG dense storage offsets for PATHS_P (l1,l2,l3):
// p0 (0,0,0) off 0   | p1 (0,1,1) off 1  | p2 (0,2,2) off 10 | p3 (1,0,1) off 35
// p4 (1,1,0) off 44  | p5 (1,1,2) off 53 | p6 (1,2,1) off 98 | p7 (2,0,2) off 143
// p8 (2,1,1) off 168 | p9 (2,2,0) off 213| p10(2,2,2) off 238  -> total 363

__device__ __forceinline__ float silu_f(float x) { return x / (1.f + expf(-x)); }

// ================= CG init: LDS-parallel, one 512-thread block =================
__device__ __forceinline__ void c2r_elem(int l, int r, int c, double& re, double& im) {
  re = 0.0; im = 0.0;
  int mr = r - l, mc = c - l;
  const double s = 0.70710678118654752440;
  if (mr == 0) { if (mc == 0) re = 1.0; return; }
  if (mr > 0) {
    double sg = (mr & 1) ? -1.0 : 1.0;
    if (mc == mr) re = sg * s;
    else if (mc == -mr) re = s;
  } else {
    int m = -mr;
    double sg = (m & 1) ? -1.0 : 1.0;
    if (mc == m) im = -sg * s;
    else if (mc == -m) im = s;
  }
}

__constant__ int CG_L1[11] = {0,0,0,1,1,1,1,2,2,2,2};
__constant__ int CG_L2[11] = {0,1,2,0,1,1,2,0,1,2,2};
__constant__ int CG_L3[11] = {0,1,2,1,0,2,1,2,1,0,2};
__constant__ int CG_OFF[11] = {0,1,10,35,44,53,98,143,168,213,238};
__constant__ double CG_FACT[8] = {1.,1.,2.,6.,24.,120.,720.,5040.};

__launch_bounds__(512)
__global__ void k_cg(float* __restrict__ cg) {
  __shared__ double CCs[11][125];
  __shared__ double trs[11*125];
  __shared__ double tis[11*125];
  __shared__ double scaleL[11];
  __shared__ int useRL[11];
  int tid = threadIdx.x;

  for (int i = tid; i < 11*125; i += 512) CCs[i/125][i%125] = 0.0;
  __syncthreads();

  for (int idx = tid; idx < 11*25; idx += 512) {
    int p = idx / 25, r = idx % 25;
    int i1 = r / 5, i2 = r % 5;
    int l1 = CG_L1[p], l2 = CG_L2[p], l3 = CG_L3[p];
    int d2 = 2*l2+1, d3 = 2*l3+1;
    if (i1 >= 2*l1+1 || i2 >= d2) continue;
    int m1 = i1 - l1, m2 = i2 - l2, m3 = m1 + m2;
    if (m3 < -l3 || m3 > l3) continue;
    double pre0 = sqrt((double)(2*l3+1) * CG_FACT[l3+l1-l2] * CG_FACT[l3-l1+l2]
                       * CG_FACT[l1+l2-l3] / CG_FACT[l1+l2+l3+1]);
    double pre = pre0 * sqrt(CG_FACT[l3+m3]*CG_FACT[l3-m3]*CG_FACT[l1-m1]
                             *CG_FACT[l1+m1]*CG_FACT[l2-m2]*CG_FACT[l2+m2]);
    double ssum = 0.0;
    for (int k = 0; k <= l1 + l2 - l3; k++) {
      int a2 = l1-m1-k, a3 = l2+m2-k, a4 = l3-l2+m1+k, a5 = l3-l1-m2+k;
      if (a2 < 0 || a3 < 0 || a4 < 0 || a5 < 0) continue;
      double den = CG_FACT[k]*CG_FACT[l1+l2-l3-k]*CG_FACT[a2]*CG_FACT[a3]*CG_FACT[a4]*CG_FACT[a5];
      ssum += ((k & 1) ? -1.0 : 1.0) / den;
    }
    CCs[p][(i1*d2 + i2)*d3 + (m3 + l3)] = pre * ssum;
  }
  __syncthreads();

  for (int idx = tid; idx < 11*125; idx += 512) {
    int p = idx / 125, r = idx % 125;
    int a = r / 25, b = (r / 5) % 5, c = r % 5;
    int l1 = CG_L1[p], l2 = CG_L2[p], l3 = CG_L3[p];
    int d1 = 2*l1+1, d2 = 2*l2+1, d3 = 2*l3+1;
    if (a >= d1 || b >= d2 || c >= d3) continue;
    double tr = 0.0, ti = 0.0;
    for (int i = 0; i < d1; i++) for (int j = 0; j < d2; j++) {
      double a1r, a1i, a2r, a2i;
      c2r_elem(l1, a, i, a1r, a1i); a1i = -a1i;
      c2r_elem(l2, b, j, a2r, a2i); a2i = -a2i;
      double zr = a1r*a2r - a1i*a2i, zi = a1r*a2i + a1i*a2r;
      for (int k = 0; k < d3; k++) {
        double cc = CCs[p][(i*d2 + j)*d3 + k];
        if (cc == 0.0) continue;
        double a3r, a3i;
        c2r_elem(l3, c, k, a3r, a3i);
        tr += (zr*a3r - zi*a3i) * cc;
        ti += (zr*a3i + zi*a3r) * cc;
      }
    }
    trs[idx] = tr; tis[idx] = ti;
  }
  __syncthreads();

  if (tid < 11) {
    int p = tid;
    int l1 = CG_L1[p], l2 = CG_L2[p], l3 = CG_L3[p];
    int d1 = 2*l1+1, d2 = 2*l2+1, d3 = 2*l3+1;
    double sr = 0.0, si = 0.0;
    for (int a = 0; a < d1; a++) for (int b = 0; b < d2; b++) for (int c = 0; c < d3; c++) {
      int idx = p*125 + a*25 + b*5 + c;
      sr += fabs(trs[idx]); si += fabs(tis[idx]);
    }
    int useR = (sr >= si);
    double nrm = 0.0;
    for (int a = 0; a < d1; a++) for (int b = 0; b < d2; b++) for (int c = 0; c < d3; c++) {
      int idx = p*125 + a*25 + b*5 + c;
      double v = useR ? trs[idx] : tis[idx];
      nrm += v * v;
    }
    scaleL[p] = sqrt((double)(2*l3+1)) / sqrt(nrm);
    useRL[p] = useR;
  }
  __syncthreads();

  for (int idx = tid; idx < 11*125; idx += 512) {
    int p = idx / 125, r = idx % 125;
    int a = r / 25, b = (r / 5) % 5, c = r % 5;
    int l1 = CG_L1[p], l2 = CG_L2[p], l3 = CG_L3[p];
    int d1 = 2*l1+1, d2 = 2*l2+1, d3 = 2*l3+1;
    if (a >= d1 || b >= d2 || c >= d3) continue;
    double v = useRL[p] ? trs[idx] : tis[idx];
    cg[CG_OFF[p] + (a*d2 + b)*d3 + c] = (float)(v * scaleL[p]);
  }
}

// ================= CSR build =================
__global__ void k_hist(const int* __restrict__ recv, int* __restrict__ counts) {
  int e = blockIdx.x * 256 + threadIdx.x;
  if (e < NEDGES) atomicAdd(&counts[recv[e]], 1);
}

__launch_bounds__(256)
__global__ void k_scan(const int* __restrict__ counts, int* __restrict__ off, int* __restrict__ cursor) {
  __shared__ int part[256];
  __shared__ int base[257];
  int t = threadIdx.x;
  const int CH = (NNODES + 255) / 256;
  int s = 0;
  for (int i = 0; i < CH; i++) { int n = t*CH + i; if (n < NNODES) s += counts[n]; }
  part[t] = s;
  __syncthreads();
  if (t == 0) { int acc = 0; for (int i = 0; i < 256; i++) { base[i] = acc; acc += part[i]; } base[256] = acc; }
  __syncthreads();
  int run = base[t];
  for (int i = 0; i < CH; i++) {
    int n = t*CH + i;
    if (n < NNODES) { int cn = counts[n]; off[n] = run; cursor[n] = run; run += cn; }
  }
  if (t == 255) off[NNODES] = base[256];
}

__global__ void k_bucket(const int* __restrict__ recv, int* __restrict__ cursor, int* __restrict__ eidx) {
  int e = blockIdx.x * 256 + threadIdx.x;
  if (e < NEDGES) { int p = atomicAdd(&cursor[recv[e]], 1); eidx[p] = e; }
}

// ================= helpers =================
template<int D1, int D2, int D3, int BASE, int ROWS>
__device__ __forceinline__ void tp_acc(const float (&yv)[D1], const float* shv, float wsc,
                                       const float* cgs, int offc, float (&acc)[ROWS]) {
  float m[D3];
#pragma unroll
  for (int mm = 0; mm < D3; mm++) m[mm] = 0.f;
#pragma unroll
  for (int i = 0; i < D1; i++)
#pragma unroll
    for (int j = 0; j < D2; j++) {
      float t = yv[i] * shv[j];
#pragma unroll
      for (int mm = 0; mm < D3; mm++) m[mm] += t * cgs[offc + (i*D2 + j)*D3 + mm];
    }
  float s = wsc * (1.f / 16.f);  // / AVG_NN
#pragma unroll
  for (int mm = 0; mm < D3; mm++) acc[BASE + mm] += s * m[mm];
}

template<int D1, int D2, int D3>
__device__ __forceinline__ void pb_path(float cp, const float (&T)[D1], const float (&A)[D2],
                                        float (&NN)[D3], const float* cgs, int offc) {
#pragma unroll
  for (int i = 0; i < D1; i++)
#pragma unroll
    for (int j = 0; j < D2; j++) {
      float t = cp * T[i] * A[j];
#pragma unroll
      for (int mm = 0; mm < D3; mm++) NN[mm] += t * cgs[offc + (i*D2 + j)*D3 + mm];
    }
}

// ================= node pre: y = up(x), sc = elem-skip(x) =================
template<int B>
__launch_bounds__(256)
__global__ void k_node_pre(const float* __restrict__ x0, const float* __restrict__ x1,
                           const int* __restrict__ elem,
                           const float* __restrict__ upl0, const float* __restrict__ upl1,
                           const float* __restrict__ scw0, const float* __restrict__ scw1,
                           float* __restrict__ y0, float* __restrict__ y1,
                           float* __restrict__ sc0, float* __restrict__ sc1) {
  __shared__ float xs[4][4][64];
  int wid = threadIdx.x >> 6, lane = threadIdx.x & 63;
  int n = blockIdx.x * 4 + wid;
  xs[wid][0][lane] = x0[n*64 + lane];
  if (B) {
#pragma unroll
    for (int i = 0; i < 3; i++) xs[wid][1 + i][lane] = x1[(n*3 + i)*64 + lane];
  }
  __syncthreads();
  int z = elem[n];
  float a0 = 0.f, s0 = 0.f;
  float a1[3] = {0.f,0.f,0.f}, s1[3] = {0.f,0.f,0.f};
  for (int k = 0; k < 64; k++) {
    float xv = xs[wid][0][k];
    a0 += xv * upl0[k*64 + lane];
    s0 += xv * scw0[(z*64 + k)*64 + lane];
    if (B) {
      float uv = upl1[k*64 + lane];
      float sv = scw1[(z*64 + k)*64 + lane];
#pragma unroll
      for (int i = 0; i < 3; i++) {
        float xv1 = xs[wid][1 + i][k];
        a1[i] += xv1 * uv;
        s1[i] += xv1 * sv;
      }
    }
  }
  y0[n*64 + lane] = a0;
  sc0[n*64 + lane] = s0;
  if (B) {
#pragma unroll
    for (int i = 0; i < 3; i++) {
      y1[(n*3 + i)*64 + lane] = a1[i];
      sc1[(n*3 + i)*64 + lane] = s1[i];
    }
  }
}

// ================= edge gather: one wave per node, CSR edge list =================
// Agg rows, B=0 (9): p0->0 ; p1->1+m ; p2->4+m
// Agg rows, B=1 (21): l3=0:{p0->0,p4->1} l3=1:{p1->2+m,p3->5+m,p6->8+m} l3=2:{p2->11+m,p5->16+m}
template<int B>
__launch_bounds__(256)
__global__ void k_edge_gather(const float* __restrict__ er, const float* __restrict__ esh,
                              const int* __restrict__ senders,
                              const int* __restrict__ off, const int* __restrict__ eidx,
                              const float* __restrict__ w0, const float* __restrict__ w1,
                              const float* __restrict__ w2, const float* __restrict__ wo,
                              const float* __restrict__ y0, const float* __restrict__ y1,
                              const float* __restrict__ cg, float* __restrict__ Agg) {
  constexpr int NP = B ? 7 : 3;
  constexpr int ROWS = B ? 21 : 9;
  __shared__ __align__(16) float hs[4][2][64][4];  // [wave][pingpong][k][edge]
  __shared__ float cgs[363];
  int wid = threadIdx.x >> 6, lane = threadIdx.x & 63;
  for (int i = threadIdx.x; i < 363; i += 256) cgs[i] = cg[i];
  __syncthreads();   // the ONLY block barrier; waves run independently after

  int n = blockIdx.x * 4 + wid;
  int beg = off[n];
  int deg = off[n + 1] - beg;

  float acc[ROWS];
#pragma unroll
  for (int r = 0; r < ROWS; r++) acc[r] = 0.f;

  for (int c0 = 0; c0 < deg; c0 += 4) {
    int ej[4];
#pragma unroll
    for (int j = 0; j < 4; j++) {
      int idx = c0 + j;
      ej[j] = (idx < deg) ? eidx[beg + idx] : -1;
    }
    // layer 1: R=8 -> 64 (invalid edges -> 0; silu(0)=0 propagates to wacc=0)
    {
      float o[4];
#pragma unroll
      for (int j = 0; j < 4; j++) {
        if (ej[j] >= 0) {
          float a = 0.f;
#pragma unroll
          for (int r = 0; r < 8; r++) a += er[ej[j]*8 + r] * w0[r*64 + lane];
          o[j] = silu_f(a);
        } else o[j] = 0.f;
      }
      *(float4*)&hs[wid][0][lane][0] = make_float4(o[0], o[1], o[2], o[3]);
    }
    // layer 2: 64 -> 64 (within-wave LDS RAW, no block barrier needed)
    {
      float a0 = 0.f, a1 = 0.f, a2 = 0.f, a3 = 0.f;
      for (int k = 0; k < 64; k++) {
        float4 hv = *(const float4*)&hs[wid][0][k][0];
        float wv = w1[k*64 + lane];
        a0 += hv.x*wv; a1 += hv.y*wv; a2 += hv.z*wv; a3 += hv.w*wv;
      }
      *(float4*)&hs[wid][1][lane][0] = make_float4(silu_f(a0), silu_f(a1), silu_f(a2), silu_f(a3));
    }
    // layer 3: 64 -> 64
    {
      float a0 = 0.f, a1 = 0.f, a2 = 0.f, a3 = 0.f;
      for (int k = 0; k < 64; k++) {
        float4 hv = *(const float4*)&hs[wid][1][k][0];
        float wv = w2[k*64 + lane];
        a0 += hv.x*wv; a1 += hv.y*wv; a2 += hv.z*wv; a3 += hv.w*wv;
      }
      *(float4*)&hs[wid][0][lane][0] = make_float4(silu_f(a0), silu_f(a1), silu_f(a2), silu_f(a3));
    }
    // output layer: 64 -> NP*64 (no activation)
    float wacc[NP][4];
#pragma unroll
    for (int p = 0; p < NP; p++) { wacc[p][0] = 0.f; wacc[p][1] = 0.f; wacc[p][2] = 0.f; wacc[p][3] = 0.f; }
    for (int k = 0; k < 64; k++) {
      float4 hv = *(const float4*)&hs[wid][0][k][0];
#pragma unroll
      for (int p = 0; p < NP; p++) {
        float wv = wo[k*(NP*64) + p*64 + lane];
        wacc[p][0] += hv.x*wv; wacc[p][1] += hv.y*wv; wacc[p][2] += hv.z*wv; wacc[p][3] += hv.w*wv;
      }
    }

    // tensor product accumulate (registers, no atomics)
#pragma unroll
    for (int j = 0; j < 4; j++) {
      if (ej[j] < 0) continue;
      int e = ej[j];
      int sn = senders[e];
      float y0a[1] = { y0[sn*64 + lane] };
      float sh[9];
#pragma unroll
      for (int q = 0; q < 9; q++) sh[q] = esh[e*9 + q];
      if (B == 0) {
        tp_acc<1,1,1,0>(y0a, sh + 0, wacc[0][j], cgs, 0,  acc);
        tp_acc<1,3,3,1>(y0a, sh + 1, wacc[1][j], cgs, 1,  acc);
        tp_acc<1,5,5,4>(y0a, sh + 4, wacc[2][j], cgs, 10, acc);
      } else {
        tp_acc<1,1,1,0> (y0a, sh + 0, wacc[0][j], cgs, 0,  acc);
        tp_acc<1,3,3,2> (y0a, sh + 1, wacc[1][j], cgs, 1,  acc);
        tp_acc<1,5,5,11>(y0a, sh + 4, wacc[2][j], cgs, 10, acc);
        float y1a[3];
#pragma unroll
        for (int i = 0; i < 3; i++) y1a[i] = y1[(sn*3 + i)*64 + lane];
        tp_acc<3,1,3,5> (y1a, sh + 0, wacc[NP>3?3:0][j], cgs, 35, acc);
        tp_acc<3,3,1,1> (y1a, sh + 1, wacc[NP>3?4:0][j], cgs, 44, acc);
        tp_acc<3,3,5,16>(y1a, sh + 1, wacc[NP>3?5:0][j], cgs, 53, acc);
        tp_acc<3,5,3,8> (y1a, sh + 4, wacc[NP>3?6:0][j], cgs, 98, acc);
      }
    }
  }

#pragma unroll
  for (int r = 0; r < ROWS; r++)
    Agg[((size_t)n*ROWS + r)*64 + lane] = acc[r];
}

// ================= node post: lin(Agg) -> A, product basis, out =================
template<int B>
__launch_bounds__(256)
__global__ void k_node_post(const float* __restrict__ Agg, const int* __restrict__ elem,
                            const float* __restrict__ lin0, const float* __restrict__ lin1,
                            const float* __restrict__ lin2,
                            const float* __restrict__ w2p, const float* __restrict__ w3p,
                            const float* __restrict__ wnu,
                            const float* __restrict__ plin0, const float* __restrict__ plin1,
                            const float* __restrict__ sc0, const float* __restrict__ sc1,
                            const float* __restrict__ cg,
                            float* __restrict__ x0n, float* __restrict__ x1n,
                            float* __restrict__ out, int obase) {
  constexpr int P0 = B ? 2 : 1, P1 = B ? 3 : 1, P2 = B ? 2 : 1;
  constexpr int ROWS = P0 + 3*P1 + 5*P2;
  constexpr int BASE1 = P0, BASE2 = P0 + 3*P1;
  __shared__ float st[4][ROWS][64];
  __shared__ float cgs[363];
  __shared__ float Bs[4][4][64];
  int wid = threadIdx.x >> 6, lane = threadIdx.x & 63;
  int n = blockIdx.x * 4 + wid;
  for (int i = threadIdx.x; i < 363; i += 256) cgs[i] = cg[i];
#pragma unroll
  for (int r = 0; r < ROWS; r++) st[wid][r][lane] = Agg[((size_t)n*ROWS + r)*64 + lane];
  __syncthreads();
  int z = elem[n];

  float A0[1], A1[3], A2[5];
  {
    float a = 0.f;
    for (int k = 0; k < 64; k++) {
#pragma unroll
      for (int P = 0; P < P0; P++) a += st[wid][P][k] * lin0[(P*64 + k)*64 + lane];
    }
    A0[0] = a;
  }
#pragma unroll
  for (int i = 0; i < 3; i++) {
    float a = 0.f;
    for (int k = 0; k < 64; k++) {
#pragma unroll
      for (int P = 0; P < P1; P++) a += st[wid][BASE1 + P*3 + i][k] * lin1[(P*64 + k)*64 + lane];
    }
    A1[i] = a;
  }
#pragma unroll
  for (int i = 0; i < 5; i++) {
    float a = 0.f;
    for (int k = 0; k < 64; k++) {
#pragma unroll
      for (int P = 0; P < P2; P++) a += st[wid][BASE2 + P*5 + i][k] * lin2[(P*64 + k)*64 + lane];
    }
    A2[i] = a;
  }

  float T0[1] = {A0[0]};
  float T1[3], T2[5];
#pragma unroll
  for (int i = 0; i < 3; i++) T1[i] = A1[i];
#pragma unroll
  for (int i = 0; i < 5; i++) T2[i] = A2[i];
  float s10 = 0.f, s11[3] = {0.f,0.f,0.f}, s20 = 0.f, s21[3] = {0.f,0.f,0.f};
#pragma unroll
  for (int it = 0; it < 2; it++) {
    const float* wp = it ? w3p : w2p;
    float c[11];
#pragma unroll
    for (int p = 0; p < 11; p++) c[p] = wp[(z*11 + p)*64 + lane];
    float n0[1] = {0.f}, n1[3] = {0.f,0.f,0.f}, n2[5] = {0.f,0.f,0.f,0.f,0.f};
    pb_path<1,1,1>(c[0],  T0, A0, n0, cgs, 0);
    pb_path<1,3,3>(c[1],  T0, A1, n1, cgs, 1);
    pb_path<1,5,5>(c[2],  T0, A2, n2, cgs, 10);
    pb_path<3,1,3>(c[3],  T1, A0, n1, cgs, 35);
    pb_path<3,3,1>(c[4],  T1, A1, n0, cgs, 44);
    pb_path<3,3,5>(c[5],  T1, A1, n2, cgs, 53);
    pb_path<3,5,3>(c[6],  T1, A2, n1, cgs, 98);
    pb_path<5,1,5>(c[7],  T2, A0, n2, cgs, 143);
    pb_path<5,3,3>(c[8],  T2, A1, n1, cgs, 168);
    pb_path<5,5,1>(c[9],  T2, A2, n0, cgs, 213);
    pb_path<5,5,5>(c[10], T2, A2, n2, cgs, 238);
    T0[0] = n0[0];
#pragma unroll
    for (int i = 0; i < 3; i++) T1[i] = n1[i];
#pragma unroll
    for (int i = 0; i < 5; i++) T2[i] = n2[i];
    if (it == 0) {
      s10 = n0[0];
#pragma unroll
      for (int i = 0; i < 3; i++) s11[i] = n1[i];
    } else {
      s20 = n0[0];
#pragma unroll
      for (int i = 0; i < 3; i++) s21[i] = n1[i];
    }
  }

  float c00 = wnu[((z*3 + 0)*2 + 0)*64 + lane];
  float c10 = wnu[((z*3 + 1)*2 + 0)*64 + lane];
  float c20 = wnu[((z*3 + 2)*2 + 0)*64 + lane];
  float c01 = wnu[((z*3 + 0)*2 + 1)*64 + lane];
  float c11 = wnu[((z*3 + 1)*2 + 1)*64 + lane];
  float c21 = wnu[((z*3 + 2)*2 + 1)*64 + lane];
  float b0v = c00*A0[0] + c10*s10 + c20*s20;
  float b1v[3];
#pragma unroll
  for (int i = 0; i < 3; i++) b1v[i] = c01*A1[i] + c11*s11[i] + c21*s21[i];
  Bs[wid][0][lane] = b0v;
#pragma unroll
  for (int i = 0; i < 3; i++) Bs[wid][1 + i][lane] = b1v[i];
  __syncthreads();

  float x0v = 0.f, x1v[3] = {0.f,0.f,0.f};
  for (int k = 0; k < 64; k++) {
    float p0v = plin0[k*64 + lane];
    float p1v = plin1[k*64 + lane];
    x0v += Bs[wid][0][k] * p0v;
#pragma unroll
    for (int i = 0; i < 3; i++) x1v[i] += Bs[wid][1 + i][k] * p1v;
  }
  x0v += sc0[n*64 + lane];
  if (B) {
#pragma unroll
    for (int i = 0; i < 3; i++) x1v[i] += sc1[(n*3 + i)*64 + lane];
  }
  if (B == 0) {
    x0n[n*64 + lane] = x0v;
#pragma unroll
    for (int i = 0; i < 3; i++) x1n[(n*3 + i)*64 + lane] = x1v[i];
  }
  out[(size_t)n*512 + obase + lane] = x0v;
#pragma unroll
  for (int i = 0; i < 3; i++)
    out[(size_t)n*512 + obase + 64 + lane*3 + i] = x1v[i];
}

// ================= launch =================
extern "C" void kernel_launch(void* const* d_in, const int* in_sizes, int n_in,
                              void* d_out, int out_size, void* d_ws, size_t ws_size,
                              hipStream_t stream) {
  const float* node_feats  = (const float*)d_in[0];
  const int*   node_elem   = (const int*)  d_in[1];
  const float* edge_sh     = (const float*)d_in[2];
  const float* edge_radial = (const float*)d_in[3];
  const int*   senders     = (const int*)  d_in[4];
  const int*   receivers   = (const int*)  d_in[5];
  const float* up0_l0   = (const float*)d_in[6];
  const float* r0_w0    = (const float*)d_in[7];
  const float* r0_w1    = (const float*)d_in[8];
  const float* r0_w2    = (const float*)d_in[9];
  const float* r0_wo    = (const float*)d_in[10];
  const float* lin0_l0  = (const float*)d_in[11];
  const float* lin0_l1  = (const float*)d_in[12];
  const float* lin0_l2  = (const float*)d_in[13];
  const float* sc0_l0   = (const float*)d_in[14];
  const float* p0_w2    = (const float*)d_in[15];
  const float* p0_w3    = (const float*)d_in[16];
  const float* p0_wnu   = (const float*)d_in[17];
  const float* p0_lin_l0= (const float*)d_in[18];
  const float* p0_lin_l1= (const float*)d_in[19];
  const float* up1_l0   = (const float*)d_in[20];
  const float* up1_l1   = (const float*)d_in[21];
  const float* r1_w0    = (const float*)d_in[22];
  const float* r1_w1    = (const float*)d_in[23];
  const float* r1_w2    = (const float*)d_in[24];
  const float* r1_wo    = (const float*)d_in[25];
  const float* lin1_l0  = (const float*)d_in[26];
  const float* lin1_l1  = (const float*)d_in[27];
  const float* lin1_l2  = (const float*)d_in[28];
  const float* sc1_l0   = (const float*)d_in[29];
  const float* sc1_l1   = (const float*)d_in[30];
  const float* p1_w2    = (const float*)d_in[31];
  const float* p1_w3    = (const float*)d_in[32];
  const float* p1_wnu   = (const float*)d_in[33];
  const float* p1_lin_l0= (const float*)d_in[34];
  const float* p1_lin_l1= (const float*)d_in[35];

  float* ws  = (float*)d_ws;
  float* cg  = ws + WS_CG;
  float* y0  = ws + WS_Y0;
  float* y1  = ws + WS_Y1;
  float* sc0 = ws + WS_SC0;
  float* sc1 = ws + WS_SC1;
  float* x0n = ws + WS_X0N;
  float* x1n = ws + WS_X1N;
  float* Agg = ws + WS_AGG;
  int* counts = (int*)(ws + WS_CSR);
  int* off    = counts + NNODES;       // NNODES+1
  int* cursor = off + NNODES + 1;      // NNODES
  int* eidx   = cursor + NNODES;       // NEDGES
  float* out = (float*)d_out;

  k_cg<<<1, 512, 0, stream>>>(cg);

  // ---- CSR build (shared by both blocks) ----
  hipMemsetAsync(counts, 0, NNODES * sizeof(int), stream);
  k_hist<<<(NEDGES + 255) / 256, 256, 0, stream>>>(receivers, counts);
  k_scan<<<1, 256, 0, stream>>>(counts, off, cursor);
  k_bucket<<<(NEDGES + 255) / 256, 256, 0, stream>>>(receivers, cursor, eidx);

  // ---- interaction block 0 ----
  k_node_pre<0><<<NNODES/4, 256, 0, stream>>>(node_feats, nullptr, node_elem,
                                              up0_l0, nullptr, sc0_l0, nullptr,
                                              y0, y1, sc0, sc1);
  k_edge_gather<0><<<NNODES/4, 256, 0, stream>>>(edge_radial, edge_sh, senders, off, eidx,
                                                 r0_w0, r0_w1, r0_w2, r0_wo, y0, y1, cg, Agg);
  k_node_post<0><<<NNODES/4, 256, 0, stream>>>(Agg, node_elem, lin0_l0, lin0_l1, lin0_l2,
                                               p0_w2, p0_w3, p0_wnu, p0_lin_l0, p0_lin_l1,
                                               sc0, sc1, cg, x0n, x1n, out, 0);

  // ---- interaction block 1 ----
  k_node_pre<1><<<NNODES/4, 256, 0, stream>>>(x0n, x1n, node_elem,
                                              up1_l0, up1_l1, sc1_l0, sc1_l1,
                                              y0, y1, sc0, sc1);
  k_edge_gather<1><<<NNODES/4, 256, 0, stream>>>(edge_radial, edge_sh, senders, off, eidx,
                                                 r1_w0, r1_w1, r1_w2, r1_wo, y0, y1, cg, Agg);
  k_node_post<1><<<NNODES/4, 256, 0, stream>>>(Agg, node_elem, lin1_l0, lin1_l1, lin1_l2,
                                               p1_w2, p1_w3, p1_wnu, p1_lin_l0, p1_lin_l1,
                                               sc0, sc1, cg, x0n, x1n, out, 256);
}

// Round 6
// 2285.130 us; speedup vs baseline: 1.7981x; 1.7981x over previous
//
#include <hip/hip_runtime.h>
#include <math.h>

#define NNODES 16000
#define NEDGES 256000

// ---------------- ws layout (float element offsets) ----------------
// cg | y0 | y1 | sc0 | sc1 | BIG{ Agg(<=21 rows) ; x0n/x1n aliased after Agg9 } | CSR ints
// x0n/x1n: written ONLY by k_node_post<0>, read ONLY by k_node_pre<1>.
// The 21-row Agg memset clobbers them, so it must run AFTER k_node_pre<1>.
#define WS_CG   0
#define WS_Y0   512
#define WS_Y1   (WS_Y0 + NNODES*64)
#define WS_SC0  (WS_Y1 + NNODES*192)
#define WS_SC1  (WS_SC0 + NNODES*64)
#define WS_BIG  (WS_SC1 + NNODES*192)
#define WS_AGG  WS_BIG
#define WS_X0N  (WS_BIG + NNODES*9*64)
#define WS_X1N  (WS_X0N + NNODES*64)
#define WS_CSR  (WS_BIG + NNODES*21*64)  // int region starts here
// ints: counts[N] | off[N+1] | cursor[N] | eidx[E] ~ 1.2 MB ; total ~ 120 MB

// CG dense storage offsets for PATHS_P (l1,l2,l3):
// p0 (0,0,0) off 0   | p1 (0,1,1) off 1  | p2 (0,2,2) off 10 | p3 (1,0,1) off 35
// p4 (1,1,0) off 44  | p5 (1,1,2) off 53 | p6 (1,2,1) off 98 | p7 (2,0,2) off 143
// p8 (2,1,1) off 168 | p9 (2,2,0) off 213| p10(2,2,2) off 238  -> total 363

__device__ __forceinline__ float silu_f(float x) { return x / (1.f + expf(-x)); }

// ================= CG init: LDS-parallel, one 512-thread block =================
__device__ __forceinline__ void c2r_elem(int l, int r, int c, double& re, double& im) {
  re = 0.0; im = 0.0;
  int mr = r - l, mc = c - l;
  const double s = 0.70710678118654752440;
  if (mr == 0) { if (mc == 0) re = 1.0; return; }
  if (mr > 0) {
    double sg = (mr & 1) ? -1.0 : 1.0;
    if (mc == mr) re = sg * s;
    else if (mc == -mr) re = s;
  } else {
    int m = -mr;
    double sg = (m & 1) ? -1.0 : 1.0;
    if (mc == m) im = -sg * s;
    else if (mc == -m) im = s;
  }
}

__constant__ int CG_L1[11] = {0,0,0,1,1,1,1,2,2,2,2};
__constant__ int CG_L2[11] = {0,1,2,0,1,1,2,0,1,2,2};
__constant__ int CG_L3[11] = {0,1,2,1,0,2,1,2,1,0,2};
__constant__ int CG_OFF[11] = {0,1,10,35,44,53,98,143,168,213,238};
__constant__ double CG_FACT[8] = {1.,1.,2.,6.,24.,120.,720.,5040.};

__launch_bounds__(512)
__global__ void k_cg(float* __restrict__ cg) {
  __shared__ double CCs[11][125];
  __shared__ double trs[11*125];
  __shared__ double tis[11*125];
  __shared__ double scaleL[11];
  __shared__ int useRL[11];
  int tid = threadIdx.x;

  for (int i = tid; i < 11*125; i += 512) CCs[i/125][i%125] = 0.0;
  __syncthreads();

  for (int idx = tid; idx < 11*25; idx += 512) {
    int p = idx / 25, r = idx % 25;
    int i1 = r / 5, i2 = r % 5;
    int l1 = CG_L1[p], l2 = CG_L2[p], l3 = CG_L3[p];
    int d2 = 2*l2+1, d3 = 2*l3+1;
    if (i1 >= 2*l1+1 || i2 >= d2) continue;
    int m1 = i1 - l1, m2 = i2 - l2, m3 = m1 + m2;
    if (m3 < -l3 || m3 > l3) continue;
    double pre0 = sqrt((double)(2*l3+1) * CG_FACT[l3+l1-l2] * CG_FACT[l3-l1+l2]
                       * CG_FACT[l1+l2-l3] / CG_FACT[l1+l2+l3+1]);
    double pre = pre0 * sqrt(CG_FACT[l3+m3]*CG_FACT[l3-m3]*CG_FACT[l1-m1]
                             *CG_FACT[l1+m1]*CG_FACT[l2-m2]*CG_FACT[l2+m2]);
    double ssum = 0.0;
    for (int k = 0; k <= l1 + l2 - l3; k++) {
      int a2 = l1-m1-k, a3 = l2+m2-k, a4 = l3-l2+m1+k, a5 = l3-l1-m2+k;
      if (a2 < 0 || a3 < 0 || a4 < 0 || a5 < 0) continue;
      double den = CG_FACT[k]*CG_FACT[l1+l2-l3-k]*CG_FACT[a2]*CG_FACT[a3]*CG_FACT[a4]*CG_FACT[a5];
      ssum += ((k & 1) ? -1.0 : 1.0) / den;
    }
    CCs[p][(i1*d2 + i2)*d3 + (m3 + l3)] = pre * ssum;
  }
  __syncthreads();

  for (int idx = tid; idx < 11*125; idx += 512) {
    int p = idx / 125, r = idx % 125;
    int a = r / 25, b = (r / 5) % 5, c = r % 5;
    int l1 = CG_L1[p], l2 = CG_L2[p], l3 = CG_L3[p];
    int d1 = 2*l1+1, d2 = 2*l2+1, d3 = 2*l3+1;
    if (a >= d1 || b >= d2 || c >= d3) continue;
    double tr = 0.0, ti = 0.0;
    for (int i = 0; i < d1; i++) for (int j = 0; j < d2; j++) {
      double a1r, a1i, a2r, a2i;
      c2r_elem(l1, a, i, a1r, a1i); a1i = -a1i;
      c2r_elem(l2, b, j, a2r, a2i); a2i = -a2i;
      double zr = a1r*a2r - a1i*a2i, zi = a1r*a2i + a1i*a2r;
      for (int k = 0; k < d3; k++) {
        double cc = CCs[p][(i*d2 + j)*d3 + k];
        if (cc == 0.0) continue;
        double a3r, a3i;
        c2r_elem(l3, c, k, a3r, a3i);
        tr += (zr*a3r - zi*a3i) * cc;
        ti += (zr*a3i + zi*a3r) * cc;
      }
    }
    trs[idx] = tr; tis[idx] = ti;
  }
  __syncthreads();

  if (tid < 11) {
    int p = tid;
    int l1 = CG_L1[p], l2 = CG_L2[p], l3 = CG_L3[p];
    int d1 = 2*l1+1, d2 = 2*l2+1, d3 = 2*l3+1;
    double sr = 0.0, si = 0.0;
    for (int a = 0; a < d1; a++) for (int b = 0; b < d2; b++) for (int c = 0; c < d3; c++) {
      int idx = p*125 + a*25 + b*5 + c;
      sr += fabs(trs[idx]); si += fabs(tis[idx]);
    }
    int useR = (sr >= si);
    double nrm = 0.0;
    for (int a = 0; a < d1; a++) for (int b = 0; b < d2; b++) for (int c = 0; c < d3; c++) {
      int idx = p*125 + a*25 + b*5 + c;
      double v = useR ? trs[idx] : tis[idx];
      nrm += v * v;
    }
    scaleL[p] = sqrt((double)(2*l3+1)) / sqrt(nrm);
    useRL[p] = useR;
  }
  __syncthreads();

  for (int idx = tid; idx < 11*125; idx += 512) {
    int p = idx / 125, r = idx % 125;
    int a = r / 25, b = (r / 5) % 5, c = r % 5;
    int l1 = CG_L1[p], l2 = CG_L2[p], l3 = CG_L3[p];
    int d1 = 2*l1+1, d2 = 2*l2+1, d3 = 2*l3+1;
    if (a >= d1 || b >= d2 || c >= d3) continue;
    double v = useRL[p] ? trs[idx] : tis[idx];
    cg[CG_OFF[p] + (a*d2 + b)*d3 + c] = (float)(v * scaleL[p]);
  }
}

// ================= CSR build =================
__global__ void k_hist(const int* __restrict__ recv, int* __restrict__ counts) {
  int e = blockIdx.x * 256 + threadIdx.x;
  if (e < NEDGES) atomicAdd(&counts[recv[e]], 1);
}

__launch_bounds__(256)
__global__ void k_scan(const int* __restrict__ counts, int* __restrict__ off, int* __restrict__ cursor) {
  __shared__ int part[256];
  __shared__ int base[257];
  int t = threadIdx.x;
  const int CH = (NNODES + 255) / 256;
  int s = 0;
  for (int i = 0; i < CH; i++) { int n = t*CH + i; if (n < NNODES) s += counts[n]; }
  part[t] = s;
  __syncthreads();
  if (t == 0) { int acc = 0; for (int i = 0; i < 256; i++) { base[i] = acc; acc += part[i]; } base[256] = acc; }
  __syncthreads();
  int run = base[t];
  for (int i = 0; i < CH; i++) {
    int n = t*CH + i;
    if (n < NNODES) { int cn = counts[n]; off[n] = run; cursor[n] = run; run += cn; }
  }
  if (t == 255) off[NNODES] = base[256];
}

__global__ void k_bucket(const int* __restrict__ recv, int* __restrict__ cursor, int* __restrict__ eidx) {
  int e = blockIdx.x * 256 + threadIdx.x;
  if (e < NEDGES) { int p = atomicAdd(&cursor[recv[e]], 1); eidx[p] = e; }
}

// ================= helpers =================
template<int D1, int D2, int D3, int BASE, int ROWS>
__device__ __forceinline__ void tp_acc(const float (&yv)[D1], const float* shv, float wsc,
                                       const float* cgs, int offc, float (&acc)[ROWS]) {
  float m[D3];
#pragma unroll
  for (int mm = 0; mm < D3; mm++) m[mm] = 0.f;
#pragma unroll
  for (int i = 0; i < D1; i++)
#pragma unroll
    for (int j = 0; j < D2; j++) {
      float t = yv[i] * shv[j];
#pragma unroll
      for (int mm = 0; mm < D3; mm++) m[mm] += t * cgs[offc + (i*D2 + j)*D3 + mm];
    }
  float s = wsc * (1.f / 16.f);  // / AVG_NN
#pragma unroll
  for (int mm = 0; mm < D3; mm++) acc[BASE + mm] += s * m[mm];
}

template<int ROWS>
__device__ __forceinline__ void flush_acc(float (&acc)[ROWS], float* __restrict__ Agg,
                                          int rn, int lane) {
  float* aggn = Agg + (size_t)rn * (ROWS*64);
#pragma unroll
  for (int r = 0; r < ROWS; r++) {
    unsafeAtomicAdd(&aggn[r*64 + lane], acc[r]);
    acc[r] = 0.f;
  }
}

template<int D1, int D2, int D3>
__device__ __forceinline__ void pb_path(float cp, const float (&T)[D1], const float (&A)[D2],
                                        float (&NN)[D3], const float* cgs, int offc) {
#pragma unroll
  for (int i = 0; i < D1; i++)
#pragma unroll
    for (int j = 0; j < D2; j++) {
      float t = cp * T[i] * A[j];
#pragma unroll
      for (int mm = 0; mm < D3; mm++) NN[mm] += t * cgs[offc + (i*D2 + j)*D3 + mm];
    }
}

// ================= node pre: y = up(x), sc = elem-skip(x) =================
template<int B>
__launch_bounds__(256)
__global__ void k_node_pre(const float* __restrict__ x0, const float* __restrict__ x1,
                           const int* __restrict__ elem,
                           const float* __restrict__ upl0, const float* __restrict__ upl1,
                           const float* __restrict__ scw0, const float* __restrict__ scw1,
                           float* __restrict__ y0, float* __restrict__ y1,
                           float* __restrict__ sc0, float* __restrict__ sc1) {
  __shared__ float xs[4][4][64];
  int wid = threadIdx.x >> 6, lane = threadIdx.x & 63;
  int n = blockIdx.x * 4 + wid;
  xs[wid][0][lane] = x0[n*64 + lane];
  if (B) {
#pragma unroll
    for (int i = 0; i < 3; i++) xs[wid][1 + i][lane] = x1[(n*3 + i)*64 + lane];
  }
  __syncthreads();
  int z = elem[n];
  float a0 = 0.f, s0 = 0.f;
  float a1[3] = {0.f,0.f,0.f}, s1[3] = {0.f,0.f,0.f};
  for (int k = 0; k < 64; k++) {
    float xv = xs[wid][0][k];
    a0 += xv * upl0[k*64 + lane];
    s0 += xv * scw0[(z*64 + k)*64 + lane];
    if (B) {
      float uv = upl1[k*64 + lane];
      float sv = scw1[(z*64 + k)*64 + lane];
#pragma unroll
      for (int i = 0; i < 3; i++) {
        float xv1 = xs[wid][1 + i][k];
        a1[i] += xv1 * uv;
        s1[i] += xv1 * sv;
      }
    }
  }
  y0[n*64 + lane] = a0;
  sc0[n*64 + lane] = s0;
  if (B) {
#pragma unroll
    for (int i = 0; i < 3; i++) {
      y1[(n*3 + i)*64 + lane] = a1[i];
      sc1[(n*3 + i)*64 + lane] = s1[i];
    }
  }
}

// ================= edge kernel: receiver-sorted, register-combine scatter =================
// Wave g processes eidx[4g..4g+4) (receiver-sorted). TP messages accumulate in
// registers; atomics flush once per receiver-run (~1.25 runs/group @ deg 16)
// instead of once per edge -> ~3-4x less atomic write traffic vs round 4.
// Agg rows, B=0 (9): p0->0 ; p1->1+m ; p2->4+m
// Agg rows, B=1 (21): l3=0:{p0->0,p4->1} l3=1:{p1->2+m,p3->5+m,p6->8+m} l3=2:{p2->11+m,p5->16+m}
template<int B>
__launch_bounds__(256)
__global__ void k_edge(const float* __restrict__ er, const float* __restrict__ esh,
                       const int* __restrict__ senders, const int* __restrict__ receivers,
                       const int* __restrict__ eidx,
                       const float* __restrict__ w0, const float* __restrict__ w1,
                       const float* __restrict__ w2, const float* __restrict__ wo,
                       const float* __restrict__ y0, const float* __restrict__ y1,
                       const float* __restrict__ cg, float* __restrict__ Agg) {
  constexpr int NP = B ? 7 : 3;
  constexpr int ROWS = B ? 21 : 9;
  __shared__ __align__(16) float hs[4][2][64][4];  // [wave][pingpong][k][edge]
  __shared__ float cgs[363];
  int wid = threadIdx.x >> 6, lane = threadIdx.x & 63;
  for (int i = threadIdx.x; i < 363; i += 256) cgs[i] = cg[i];
  __syncthreads();   // only block barrier (cgs staging); hs is per-wave

  int base = (blockIdx.x * 4 + wid) * 4;
  int ej[4], rn[4];
#pragma unroll
  for (int j = 0; j < 4; j++) {
    int e = __builtin_amdgcn_readfirstlane(eidx[base + j]);
    ej[j] = e;
    rn[j] = __builtin_amdgcn_readfirstlane(receivers[e]);
  }

  // layer 1: R=8 -> 64
  {
    float o[4];
#pragma unroll
    for (int j = 0; j < 4; j++) {
      float a = 0.f;
#pragma unroll
      for (int r = 0; r < 8; r++) a += er[ej[j]*8 + r] * w0[r*64 + lane];
      o[j] = silu_f(a);
    }
    *(float4*)&hs[wid][0][lane][0] = make_float4(o[0], o[1], o[2], o[3]);
  }
  // layer 2: 64 -> 64 (within-wave LDS RAW; no block barrier needed)
  {
    float a0 = 0.f, a1 = 0.f, a2 = 0.f, a3 = 0.f;
    for (int k = 0; k < 64; k++) {
      float4 hv = *(const float4*)&hs[wid][0][k][0];
      float wv = w1[k*64 + lane];
      a0 += hv.x*wv; a1 += hv.y*wv; a2 += hv.z*wv; a3 += hv.w*wv;
    }
    *(float4*)&hs[wid][1][lane][0] = make_float4(silu_f(a0), silu_f(a1), silu_f(a2), silu_f(a3));
  }
  // layer 3: 64 -> 64
  {
    float a0 = 0.f, a1 = 0.f, a2 = 0.f, a3 = 0.f;
    for (int k = 0; k < 64; k++) {
      float4 hv = *(const float4*)&hs[wid][1][k][0];
      float wv = w2[k*64 + lane];
      a0 += hv.x*wv; a1 += hv.y*wv; a2 += hv.z*wv; a3 += hv.w*wv;
    }
    *(float4*)&hs[wid][0][lane][0] = make_float4(silu_f(a0), silu_f(a1), silu_f(a2), silu_f(a3));
  }
  // output layer: 64 -> NP*64
  float wacc[NP][4];
#pragma unroll
  for (int p = 0; p < NP; p++) { wacc[p][0] = 0.f; wacc[p][1] = 0.f; wacc[p][2] = 0.f; wacc[p][3] = 0.f; }
  for (int k = 0; k < 64; k++) {
    float4 hv = *(const float4*)&hs[wid][0][k][0];
#pragma unroll
    for (int p = 0; p < NP; p++) {
      float wv = wo[k*(NP*64) + p*64 + lane];
      wacc[p][0] += hv.x*wv; wacc[p][1] += hv.y*wv; wacc[p][2] += hv.z*wv; wacc[p][3] += hv.w*wv;
    }
  }

  // tensor product -> register accumulate, flush per receiver-run
  float acc[ROWS];
#pragma unroll
  for (int r = 0; r < ROWS; r++) acc[r] = 0.f;
#pragma unroll
  for (int j = 0; j < 4; j++) {
    if (j > 0 && rn[j] != rn[j-1]) flush_acc<ROWS>(acc, Agg, rn[j-1], lane);
    int e = ej[j];
    int sn = senders[e];
    float y0a[1] = { y0[sn*64 + lane] };
    float sh[9];
#pragma unroll
    for (int q = 0; q < 9; q++) sh[q] = esh[e*9 + q];
    if constexpr (B == 0) {
      tp_acc<1,1,1,0>(y0a, sh + 0, wacc[0][j], cgs, 0,  acc);
      tp_acc<1,3,3,1>(y0a, sh + 1, wacc[1][j], cgs, 1,  acc);
      tp_acc<1,5,5,4>(y0a, sh + 4, wacc[2][j], cgs, 10, acc);
    } else {
      tp_acc<1,1,1,0> (y0a, sh + 0, wacc[0][j], cgs, 0,  acc);
      tp_acc<1,3,3,2> (y0a, sh + 1, wacc[1][j], cgs, 1,  acc);
      tp_acc<1,5,5,11>(y0a, sh + 4, wacc[2][j], cgs, 10, acc);
      float y1a[3];
#pragma unroll
      for (int i = 0; i < 3; i++) y1a[i] = y1[(sn*3 + i)*64 + lane];
      tp_acc<3,1,3,5> (y1a, sh + 0, wacc[NP-4][j], cgs, 35, acc);
      tp_acc<3,3,1,1> (y1a, sh + 1, wacc[NP-3][j], cgs, 44, acc);
      tp_acc<3,3,5,16>(y1a, sh + 1, wacc[NP-2][j], cgs, 53, acc);
      tp_acc<3,5,3,8> (y1a, sh + 4, wacc[NP-1][j], cgs, 98, acc);
    }
  }
  flush_acc<ROWS>(acc, Agg, rn[3], lane);
}

// ================= node post: lin(Agg) -> A, product basis, out =================
template<int B>
__launch_bounds__(256)
__global__ void k_node_post(const float* __restrict__ Agg, const int* __restrict__ elem,
                            const float* __restrict__ lin0, const float* __restrict__ lin1,
                            const float* __restrict__ lin2,
                            const float* __restrict__ w2p, const float* __restrict__ w3p,
                            const float* __restrict__ wnu,
                            const float* __restrict__ plin0, const float* __restrict__ plin1,
                            const float* __restrict__ sc0, const float* __restrict__ sc1,
                            const float* __restrict__ cg,
                            float* __restrict__ x0n, float* __restrict__ x1n,
                            float* __restrict__ out, int obase) {
  constexpr int P0 = B ? 2 : 1, P1 = B ? 3 : 1, P2 = B ? 2 : 1;
  constexpr int ROWS = P0 + 3*P1 + 5*P2;
  constexpr int BASE1 = P0, BASE2 = P0 + 3*P1;
  __shared__ float st[4][ROWS][64];
  __shared__ float cgs[363];
  __shared__ float Bs[4][4][64];
  int wid = threadIdx.x >> 6, lane = threadIdx.x & 63;
  int n = blockIdx.x * 4 + wid;
  for (int i = threadIdx.x; i < 363; i += 256) cgs[i] = cg[i];
#pragma unroll
  for (int r = 0; r < ROWS; r++) st[wid][r][lane] = Agg[((size_t)n*ROWS + r)*64 + lane];
  __syncthreads();
  int z = elem[n];

  float A0[1], A1[3], A2[5];
  {
    float a = 0.f;
    for (int k = 0; k < 64; k++) {
#pragma unroll
      for (int P = 0; P < P0; P++) a += st[wid][P][k] * lin0[(P*64 + k)*64 + lane];
    }
    A0[0] = a;
  }
#pragma unroll
  for (int i = 0; i < 3; i++) {
    float a = 0.f;
    for (int k = 0; k < 64; k++) {
#pragma unroll
      for (int P = 0; P < P1; P++) a += st[wid][BASE1 + P*3 + i][k] * lin1[(P*64 + k)*64 + lane];
    }
    A1[i] = a;
  }
#pragma unroll
  for (int i = 0; i < 5; i++) {
    float a = 0.f;
    for (int k = 0; k < 64; k++) {
#pragma unroll
      for (int P = 0; P < P2; P++) a += st[wid][BASE2 + P*5 + i][k] * lin2[(P*64 + k)*64 + lane];
    }
    A2[i] = a;
  }

  float T0[1] = {A0[0]};
  float T1[3], T2[5];
#pragma unroll
  for (int i = 0; i < 3; i++) T1[i] = A1[i];
#pragma unroll
  for (int i = 0; i < 5; i++) T2[i] = A2[i];
  float s10 = 0.f, s11[3] = {0.f,0.f,0.f}, s20 = 0.f, s21[3] = {0.f,0.f,0.f};
#pragma unroll
  for (int it = 0; it < 2; it++) {
    const float* wp = it ? w3p : w2p;
    float c[11];
#pragma unroll
    for (int p = 0; p < 11; p++) c[p] = wp[(z*11 + p)*64 + lane];
    float n0[1] = {0.f}, n1[3] = {0.f,0.f,0.f}, n2[5] = {0.f,0.f,0.f,0.f,0.f};
    pb_path<1,1,1>(c[0],  T0, A0, n0, cgs, 0);
    pb_path<1,3,3>(c[1],  T0, A1, n1, cgs, 1);
    pb_path<1,5,5>(c[2],  T0, A2, n2, cgs, 10);
    pb_path<3,1,3>(c[3],  T1, A0, n1, cgs, 35);
    pb_path<3,3,1>(c[4],  T1, A1, n0, cgs, 44);
    pb_path<3,3,5>(c[5],  T1, A1, n2, cgs, 53);
    pb_path<3,5,3>(c[6],  T1, A2, n1, cgs, 98);
    pb_path<5,1,5>(c[7],  T2, A0, n2, cgs, 143);
    pb_path<5,3,3>(c[8],  T2, A1, n1, cgs, 168);
    pb_path<5,5,1>(c[9],  T2, A2, n0, cgs, 213);
    pb_path<5,5,5>(c[10], T2, A2, n2, cgs, 238);
    T0[0] = n0[0];
#pragma unroll
    for (int i = 0; i < 3; i++) T1[i] = n1[i];
#pragma unroll
    for (int i = 0; i < 5; i++) T2[i] = n2[i];
    if (it == 0) {
      s10 = n0[0];
#pragma unroll
      for (int i = 0; i < 3; i++) s11[i] = n1[i];
    } else {
      s20 = n0[0];
#pragma unroll
      for (int i = 0; i < 3; i++) s21[i] = n1[i];
    }
  }

  float c00 = wnu[((z*3 + 0)*2 + 0)*64 + lane];
  float c10 = wnu[((z*3 + 1)*2 + 0)*64 + lane];
  float c20 = wnu[((z*3 + 2)*2 + 0)*64 + lane];
  float c01 = wnu[((z*3 + 0)*2 + 1)*64 + lane];
  float c11 = wnu[((z*3 + 1)*2 + 1)*64 + lane];
  float c21 = wnu[((z*3 + 2)*2 + 1)*64 + lane];
  float b0v = c00*A0[0] + c10*s10 + c20*s20;
  float b1v[3];
#pragma unroll
  for (int i = 0; i < 3; i++) b1v[i] = c01*A1[i] + c11*s11[i] + c21*s21[i];
  Bs[wid][0][lane] = b0v;
#pragma unroll
  for (int i = 0; i < 3; i++) Bs[wid][1 + i][lane] = b1v[i];
  __syncthreads();

  float x0v = 0.f, x1v[3] = {0.f,0.f,0.f};
  for (int k = 0; k < 64; k++) {
    float p0v = plin0[k*64 + lane];
    float p1v = plin1[k*64 + lane];
    x0v += Bs[wid][0][k] * p0v;
#pragma unroll
    for (int i = 0; i < 3; i++) x1v[i] += Bs[wid][1 + i][k] * p1v;
  }
  x0v += sc0[n*64 + lane];
  if (B) {
#pragma unroll
    for (int i = 0; i < 3; i++) x1v[i] += sc1[(n*3 + i)*64 + lane];
  }
  if (B == 0) {
    x0n[n*64 + lane] = x0v;
#pragma unroll
    for (int i = 0; i < 3; i++) x1n[(n*3 + i)*64 + lane] = x1v[i];
  }
  out[(size_t)n*512 + obase + lane] = x0v;
#pragma unroll
  for (int i = 0; i < 3; i++)
    out[(size_t)n*512 + obase + 64 + lane*3 + i] = x1v[i];
}

// ================= launch =================
extern "C" void kernel_launch(void* const* d_in, const int* in_sizes, int n_in,
                              void* d_out, int out_size, void* d_ws, size_t ws_size,
                              hipStream_t stream) {
  const float* node_feats  = (const float*)d_in[0];
  const int*   node_elem   = (const int*)  d_in[1];
  const float* edge_sh     = (const float*)d_in[2];
  const float* edge_radial = (const float*)d_in[3];
  const int*   senders     = (const int*)  d_in[4];
  const int*   receivers   = (const int*)  d_in[5];
  const float* up0_l0   = (const float*)d_in[6];
  const float* r0_w0    = (const float*)d_in[7];
  const float* r0_w1    = (const float*)d_in[8];
  const float* r0_w2    = (const float*)d_in[9];
  const float* r0_wo    = (const float*)d_in[10];
  const float* lin0_l0  = (const float*)d_in[11];
  const float* lin0_l1  = (const float*)d_in[12];
  const float* lin0_l2  = (const float*)d_in[13];
  const float* sc0_l0   = (const float*)d_in[14];
  const float* p0_w2    = (const float*)d_in[15];
  const float* p0_w3    = (const float*)d_in[16];
  const float* p0_wnu   = (const float*)d_in[17];
  const float* p0_lin_l0= (const float*)d_in[18];
  const float* p0_lin_l1= (const float*)d_in[19];
  const float* up1_l0   = (const float*)d_in[20];
  const float* up1_l1   = (const float*)d_in[21];
  const float* r1_w0    = (const float*)d_in[22];
  const float* r1_w1    = (const float*)d_in[23];
  const float* r1_w2    = (const float*)d_in[24];
  const float* r1_wo    = (const float*)d_in[25];
  const float* lin1_l0  = (const float*)d_in[26];
  const float* lin1_l1  = (const float*)d_in[27];
  const float* lin1_l2  = (const float*)d_in[28];
  const float* sc1_l0   = (const float*)d_in[29];
  const float* sc1_l1   = (const float*)d_in[30];
  const float* p1_w2    = (const float*)d_in[31];
  const float* p1_w3    = (const float*)d_in[32];
  const float* p1_wnu   = (const float*)d_in[33];
  const float* p1_lin_l0= (const float*)d_in[34];
  const float* p1_lin_l1= (const float*)d_in[35];

  float* ws  = (float*)d_ws;
  float* cg  = ws + WS_CG;
  float* y0  = ws + WS_Y0;
  float* y1  = ws + WS_Y1;
  float* sc0 = ws + WS_SC0;
  float* sc1 = ws + WS_SC1;
  float* x0n = ws + WS_X0N;
  float* x1n = ws + WS_X1N;
  float* Agg = ws + WS_AGG;
  int* counts = (int*)(ws + WS_CSR);
  int* off    = counts + NNODES;       // NNODES+1
  int* cursor = off + NNODES + 1;      // NNODES
  int* eidx   = cursor + NNODES;       // NEDGES
  float* out = (float*)d_out;

  k_cg<<<1, 512, 0, stream>>>(cg);

  // ---- CSR/sort build (shared by both blocks) ----
  hipMemsetAsync(counts, 0, NNODES * sizeof(int), stream);
  k_hist<<<(NEDGES + 255) / 256, 256, 0, stream>>>(receivers, counts);
  k_scan<<<1, 256, 0, stream>>>(counts, off, cursor);
  k_bucket<<<(NEDGES + 255) / 256, 256, 0, stream>>>(receivers, cursor, eidx);

  // ---- interaction block 0 ----
  k_node_pre<0><<<NNODES/4, 256, 0, stream>>>(node_feats, nullptr, node_elem,
                                              up0_l0, nullptr, sc0_l0, nullptr,
                                              y0, y1, sc0, sc1);
  hipMemsetAsync(Agg, 0, (size_t)NNODES * 9 * 64 * sizeof(float), stream);
  k_edge<0><<<NEDGES/16, 256, 0, stream>>>(edge_radial, edge_sh, senders, receivers, eidx,
                                           r0_w0, r0_w1, r0_w2, r0_wo, y0, y1, cg, Agg);
  k_node_post<0><<<NNODES/4, 256, 0, stream>>>(Agg, node_elem, lin0_l0, lin0_l1, lin0_l2,
                                               p0_w2, p0_w3, p0_wnu, p0_lin_l0, p0_lin_l1,
                                               sc0, sc1, cg, x0n, x1n, out, 0);

  // ---- interaction block 1 ----
  k_node_pre<1><<<NNODES/4, 256, 0, stream>>>(x0n, x1n, node_elem,
                                              up1_l0, up1_l1, sc1_l0, sc1_l1,
                                              y0, y1, sc0, sc1);
  hipMemsetAsync(Agg, 0, (size_t)NNODES * 21 * 64 * sizeof(float), stream);
  k_edge<1><<<NEDGES/16, 256, 0, stream>>>(edge_radial, edge_sh, senders, receivers, eidx,
                                           r1_w0, r1_w1, r1_w2, r1_wo, y0, y1, cg, Agg);
  k_node_post<1><<<NNODES/4, 256, 0, stream>>>(Agg, node_elem, lin1_l0, lin1_l1, lin1_l2,
                                               p1_w2, p1_w3, p1_wnu, p1_lin_l0, p1_lin_l1,
                                               sc0, sc1, cg, x0n, x1n, out, 256);
}